// Round 8
// baseline (382.706 us; speedup 1.0000x reference)
//
#include <hip/hip_runtime.h>

// LSTM: B=8192, T=512, H=32. R8 = INTRA-WAVE SOFTWARE PIPELINE over two groups.
// Block = 256 thr (4 waves) owns TWO 16-batch groups (A,B), skewed half a step;
// grid 256 -> 1 block/CU, 1 wave/SIMD, 4 lockstep waves.
// Every barrier segment pairs one group's latency front (frag ds_read -> MFMA)
// with the OTHER group's issue-dense gate math (14 trans + algebra):
//   seg 2t  : GATES_A(t) || MM_B(t)
//   seg 2t+1: GATES_B(t) || MM_A(t+1)
// Coverage is deterministic (same instruction stream), not HW wave arbitration
// — which R0-R7 showed fills only ~half the stall. Skew also makes h planes
// SINGLE-buffered: h_X write (seg k) and h_X read (seg k+1) never share a
// segment; next write is at seg k+2, after the read. 2 barriers/step.
// Per-group math/layout = R0 champion verbatim (absmax 2^-10): transposed MFMA
// D = W'*h via mfma_f32_16x16x32_f16, wave w owns tiles 2w,2w+1 -> 2 cells/
// lane; FP16 2-term h (hi+lo planes, chained MFMAs); k-perm pi_q(j)=j XOR 2q;
// gates pre-scaled by -log2e (i,f,o) / +2log2e (g); 10 exp2 + 4 rcp per
// GATES. Weights/consts shared across groups (same registers).

#define TT 512
#define HH 32
#define L2E 1.44269504088896340736f
#define XROW 132   // x tile row stride (floats): bank (4c+t) mod 32 -> 2-way

typedef _Float16 f16x8 __attribute__((ext_vector_type(8)));
typedef __fp16 fp16x2 __attribute__((ext_vector_type(2)));
typedef float f32x4 __attribute__((ext_vector_type(4)));
typedef float f32x2 __attribute__((ext_vector_type(2)));

__device__ __forceinline__ float fastrcp(float x) { return __builtin_amdgcn_rcpf(x); }
__device__ __forceinline__ float exp2f_(float x) { return __builtin_amdgcn_exp2f(x); }

__launch_bounds__(256, 1)
__global__ void lstm_kernel(const float* __restrict__ x,
                            const float* __restrict__ W_ih,
                            const float* __restrict__ W_hh,
                            const float* __restrict__ b_ih,
                            const float* __restrict__ b_hh,
                            const float* __restrict__ W_fc,
                            const float* __restrict__ b_fc,
                            float* __restrict__ out) {
    // single-buffered h planes per group: [qblk(4)*128 + batch(16)*8 + slot(8)]
    __shared__ _Float16 hpa[2][512];      // group A: [0]=hi, [1]=lo
    __shared__ _Float16 hpb[2][512];      // group B
    __shared__ float xbuf[2][16 * XROW];  // per-group x chunk (128 steps)

    const int tid  = threadIdx.x;
    const int lane = tid & 63;
    const int w    = tid >> 6;        // wave 0..3: owns tiles 2w, 2w+1
    const int c    = lane & 15;       // batch-in-group (MFMA n); also A m-row
    const int q    = lane >> 4;       // quad: k-block 8q; unit-block 8q
    const int base = blockIdx.x * 32; // A: base..base+15, B: base+16..base+31

    // ---- A-fragments (weights) tiles 2w+tt, single fp16, k-perm j^2q ----
    const int gate = c & 3;
    const float asc = (gate == 2) ? (2.0f * L2E) : (-L2E);
    const int wrow0 = gate * 32 + 8 * (c >> 2);
    f16x8 wah[2];
    #pragma unroll
    for (int tt = 0; tt < 2; ++tt) {
        const int t8 = 2 * w + tt;
        #pragma unroll
        for (int j = 0; j < 8; ++j) {
            const int u = 8 * q + (j ^ (2 * q));
            wah[tt][j] = (_Float16)(W_hh[(wrow0 + t8) * HH + u] * asc);
        }
    }

    // ---- per-cell consts: cell tt = (unit 8q + 2w + tt, batch c); shared A/B
    f32x4 wihs[2], bcs[2];
    #pragma unroll
    for (int tt = 0; tt < 2; ++tt) {
        const int u = 8 * q + 2 * w + tt;
        #pragma unroll
        for (int r = 0; r < 4; ++r) {
            const float sc = (r == 2) ? (2.0f * L2E) : (-L2E);
            wihs[tt][r] = W_ih[32 * r + u] * sc;
            bcs[tt][r]  = (b_ih[32 * r + u] + b_hh[32 * r + u]) * sc;
        }
    }

    // ---- zero both groups' planes (h0 = 0) ----
    #pragma unroll
    for (int i = tid; i < 512; i += 256) {
        hpa[0][i] = (_Float16)0.f; hpa[1][i] = (_Float16)0.f;
        hpb[0][i] = (_Float16)0.f; hpb[1][i] = (_Float16)0.f;
    }

    // ---- x staging: per group 16 rows x 128 floats, 2 float4/thread ----
    const int xrow = tid >> 4;            // 0..15
    const int xj4  = (tid & 15) * 4;      // 0..60
    auto stage = [&](int g, int tc) {
        #pragma unroll
        for (int s = 0; s < 2; ++s) {
            const float4 v = *(const float4*)
                &x[(size_t)(base + 16 * g + xrow) * TT + tc + xj4 + 64 * s];
            *(float4*)&xbuf[g][xrow * XROW + xj4 + 64 * s] = v;
        }
    };
    stage(0, 0);
    stage(1, 0);
    __syncthreads();

    // B-frag read offset (fp16 units); h write offset with k-perm (even slot)
    const int rdo = q * 128 + c * 8;
    const int wro = rdo + ((2 * w) ^ (2 * q));

    // ---- recurrent state ----
    f32x2 csA = {0.f, 0.f}, csB = {0.f, 0.f};
    f32x4 accA[2], accB[2];
    {   // MM_A(0): h=0 -> acc is just the input/bias term (MFMA adds zero)
        const float x0 = xbuf[0][c * XROW];
        accA[0] = wihs[0] * x0 + bcs[0];
        accA[1] = wihs[1] * x0 + bcs[1];
    }

    // GATES: acc -> cell update -> pack h -> LDS write (R0 STEP tail verbatim)
    auto GATES = [&](f32x4* acc, f32x2& cs2, _Float16* phi, _Float16* plo) {
        f32x2 Ei, Ef, G, Eo;
        Ei.x = exp2f_(acc[0][0]); Ei.y = exp2f_(acc[1][0]);
        Ef.x = exp2f_(acc[0][1]); Ef.y = exp2f_(acc[1][1]);
        G.x  = exp2f_(acc[0][2]); G.y  = exp2f_(acc[1][2]);
        Eo.x = exp2f_(acc[0][3]); Eo.y = exp2f_(acc[1][3]);
        const f32x2 one = {1.f, 1.f};
        const f32x2 aig = (one + Ei) * (G + one);
        const f32x2 af  = one + Ef;
        const f32x2 num = cs2 * aig + (G - one) * af;
        const f32x2 den = af * aig;
        f32x2 rc; rc.x = fastrcp(den.x); rc.y = fastrcp(den.y);
        const f32x2 cn = num * rc;
        cs2 = cn;
        f32x2 yc = cn * (2.0f * L2E);
        yc.x = __builtin_amdgcn_fmed3f(yc.x, -60.f, 60.f);
        yc.y = __builtin_amdgcn_fmed3f(yc.y, -60.f, 60.f);
        f32x2 C; C.x = exp2f_(yc.x); C.y = exp2f_(yc.y);
        const f32x2 hden = (C + one) * (one + Eo);
        f32x2 hr; hr.x = fastrcp(hden.x); hr.y = fastrcp(hden.y);
        const f32x2 hv = (C - one) * hr;
        union PK { fp16x2 v; int i; _Float16 e[2]; } ph, pl;
        ph.v = __builtin_amdgcn_cvt_pkrtz(hv.x, hv.y);
        pl.v = __builtin_amdgcn_cvt_pkrtz(hv.x - (float)ph.e[0],
                                          hv.y - (float)ph.e[1]);
        *(int*)&phi[wro] = ph.i;
        *(int*)&plo[wro] = pl.i;
    };

    #pragma unroll 1
    for (int t = 0; t < TT; ++t) {
        // ---- SEG EVEN: GATES_A(t) || MM_B(t) ----
        {
            const f16x8 bh = *(const f16x8*)&hpb[0][rdo];  // issue reads first
            const f16x8 bl = *(const f16x8*)&hpb[1][rdo];
            const float xc = xbuf[1][c * XROW + (t & 127)];
            GATES(accA, csA, hpa[0], hpa[1]);              // covers read latency
            accB[0] = __builtin_amdgcn_mfma_f32_16x16x32_f16(
                          wah[0], bh, wihs[0] * xc + bcs[0], 0, 0, 0);
            accB[1] = __builtin_amdgcn_mfma_f32_16x16x32_f16(
                          wah[1], bh, wihs[1] * xc + bcs[1], 0, 0, 0);
            accB[0] = __builtin_amdgcn_mfma_f32_16x16x32_f16(wah[0], bl, accB[0], 0, 0, 0);
            accB[1] = __builtin_amdgcn_mfma_f32_16x16x32_f16(wah[1], bl, accB[1], 0, 0, 0);
        }
        __syncthreads();
        if ((t & 127) == 127 && t + 1 < TT) {  // restage both chunks for t+1
            stage(0, t + 1);
            stage(1, t + 1);
            __syncthreads();
        }
        // ---- SEG ODD: GATES_B(t) || MM_A(t+1) ----
        {
            const f16x8 bh = *(const f16x8*)&hpa[0][rdo];
            const f16x8 bl = *(const f16x8*)&hpa[1][rdo];
            const float xc = xbuf[0][c * XROW + ((t + 1) & 127)];
            GATES(accB, csB, hpb[0], hpb[1]);
            accA[0] = __builtin_amdgcn_mfma_f32_16x16x32_f16(
                          wah[0], bh, wihs[0] * xc + bcs[0], 0, 0, 0);
            accA[1] = __builtin_amdgcn_mfma_f32_16x16x32_f16(
                          wah[1], bh, wihs[1] * xc + bcs[1], 0, 0, 0);
            accA[0] = __builtin_amdgcn_mfma_f32_16x16x32_f16(wah[0], bl, accA[0], 0, 0, 0);
            accA[1] = __builtin_amdgcn_mfma_f32_16x16x32_f16(wah[1], bl, accA[1], 0, 0, 0);
            // t = TT-1: this MM_A(512) is dead (reads valid h(512) planes,
            // result unused) — cheaper than a branch in the hot loop.
        }
        __syncthreads();
    }
    // h_A(512) in hpa, h_B(512) in hpb (written in segs 2*511 / 2*511+1).

    // ---- head: out[b] = h_T @ W_fc^T + b_fc (k-perm aware), both groups ----
    if (tid < 32) {
        const int g = tid >> 4;
        const int b = tid & 15;
        const _Float16* phi = g ? hpb[0] : hpa[0];
        const _Float16* plo = g ? hpb[1] : hpa[1];
        float s = b_fc[0];
        #pragma unroll
        for (int u = 0; u < 32; ++u) {
            const int qb = u >> 3;
            const int off = qb * 128 + b * 8 + ((u & 7) ^ (2 * qb));
            s += ((float)phi[off] + (float)plo[off]) * W_fc[u];
        }
        out[base + 16 * g + b] = s;
    }
}

extern "C" void kernel_launch(void* const* d_in, const int* in_sizes, int n_in,
                              void* d_out, int out_size, void* d_ws, size_t ws_size,
                              hipStream_t stream) {
    const float* x    = (const float*)d_in[0];
    const float* W_ih = (const float*)d_in[1];
    const float* W_hh = (const float*)d_in[2];
    const float* b_ih = (const float*)d_in[3];
    const float* b_hh = (const float*)d_in[4];
    const float* W_fc = (const float*)d_in[5];
    const float* b_fc = (const float*)d_in[6];
    float* out = (float*)d_out;

    const int B = 8192;
    lstm_kernel<<<B / 32, 256, 0, stream>>>(x, W_ih, W_hh, b_ih, b_hh,
                                            W_fc, b_fc, out);
}